// Round 1
// baseline (156.434 us; speedup 1.0000x reference)
//
#include <hip/hip_runtime.h>

// BERT self-attention, B=8 S=1024 D=768 H=12 DH=64, fp32 in/out.
// Strategy: (1) bf16 MFMA projection GEMM -> mixed (bf16, ws)
//           (2) flash-style fused attention, Q=K=V=mixed per (b,h)

#define D_MODEL 768
#define SEQ     1024
#define NHEAD   12
#define DHEAD   64
#define BATCH   8

typedef __attribute__((ext_vector_type(8))) short bf16x8;
typedef __attribute__((ext_vector_type(4))) short bf16x4v;
typedef __attribute__((ext_vector_type(4))) float f32x4;

__device__ __forceinline__ unsigned short f2bf(float f) {
  union { float f; unsigned u; } v; v.f = f;
  return (unsigned short)((v.u + 0x7FFFu + ((v.u >> 16) & 1u)) >> 16);
}

// ---------------------------------------------------------------------------
// Projection: mixed[m][n] = bf16( sum_k X[m][k] * W[n][k] + bias[n] )
// M = B*S = 8192, N = 768, K = 768.  BM=BN=128, BK=32.
// 256 threads = 4 waves in 2x2, each wave computes 64x64 (4x4 frags of 16x16).
// ---------------------------------------------------------------------------
__global__ __launch_bounds__(256) void proj_kernel(
    const float* __restrict__ X, const float* __restrict__ W,
    const float* __restrict__ bias, unsigned short* __restrict__ mixed)
{
  // +8 pad (row stride 40 elem = 80B) to spread frag-read banks
  __shared__ unsigned short As[128][40];
  __shared__ unsigned short Bs[128][40];

  const int tid = threadIdx.x;
  const int l   = tid & 63;
  const int w   = tid >> 6;
  const int m0  = blockIdx.x * 128;
  const int n0  = blockIdx.y * 128;
  const int wm  = (w >> 1) * 64;
  const int wn  = (w & 1) * 64;
  const int lr  = l & 15;         // fragment row/col lane index
  const int lk  = (l >> 4) * 8;   // fragment k offset

  f32x4 acc[4][4] = {};

  for (int k0 = 0; k0 < D_MODEL; k0 += 32) {
    // stage 128x32 fp32 -> bf16 for A and B (4096 elems each; 256 thr * 4 * 4)
    #pragma unroll
    for (int rr = 0; rr < 4; ++rr) {
      int p   = tid + rr * 256;
      int row = p >> 3;
      int cg  = (p & 7) * 4;
      f32x4 a  = *(const f32x4*)&X[(size_t)(m0 + row) * D_MODEL + k0 + cg];
      f32x4 bv = *(const f32x4*)&W[(size_t)(n0 + row) * D_MODEL + k0 + cg];
      bf16x4v ap, bp;
      ap[0] = (short)f2bf(a[0]);  ap[1] = (short)f2bf(a[1]);
      ap[2] = (short)f2bf(a[2]);  ap[3] = (short)f2bf(a[3]);
      bp[0] = (short)f2bf(bv[0]); bp[1] = (short)f2bf(bv[1]);
      bp[2] = (short)f2bf(bv[2]); bp[3] = (short)f2bf(bv[3]);
      *(bf16x4v*)&As[row][cg] = ap;
      *(bf16x4v*)&Bs[row][cg] = bp;
    }
    __syncthreads();

    bf16x8 af[4], bfr[4];
    #pragma unroll
    for (int am = 0; am < 4; ++am)
      af[am] = *(const bf16x8*)&As[wm + am * 16 + lr][lk];
    #pragma unroll
    for (int bn = 0; bn < 4; ++bn)
      bfr[bn] = *(const bf16x8*)&Bs[wn + bn * 16 + lr][lk];

    #pragma unroll
    for (int am = 0; am < 4; ++am)
      #pragma unroll
      for (int bn = 0; bn < 4; ++bn)
        acc[am][bn] = __builtin_amdgcn_mfma_f32_16x16x32_bf16(
            af[am], bfr[bn], acc[am][bn], 0, 0, 0);
    __syncthreads();
  }

  // epilogue: C/D layout col = lane&15, row = (lane>>4)*4 + i
  const int orow = (l >> 4) * 4;
  #pragma unroll
  for (int bn = 0; bn < 4; ++bn) {
    int   col  = n0 + wn + bn * 16 + lr;
    float bcol = bias[col];
    #pragma unroll
    for (int am = 0; am < 4; ++am) {
      #pragma unroll
      for (int i = 0; i < 4; ++i) {
        int row = m0 + wm + am * 16 + orow + i;
        mixed[(size_t)row * D_MODEL + col] = f2bf(acc[am][bn][i] + bcol);
      }
    }
  }
}

// ---------------------------------------------------------------------------
// Fused attention.  One block = 64 q rows of one (b,h); 4 waves x 16 rows.
// kv tiles of 64; X tile used as both K (Xs) and V (XTs, transposed).
// All LDS tiles padded to stride 72 elems (144B) -> frag reads <=2-way banks.
// ---------------------------------------------------------------------------
#define LP 72

__global__ __launch_bounds__(256) void attn_kernel(
    const unsigned short* __restrict__ mixed, const float* __restrict__ mask,
    float* __restrict__ out)
{
  __shared__ unsigned short Qs[64 * LP];
  __shared__ unsigned short Xs[64 * LP];
  __shared__ unsigned short XTs[64 * LP];
  __shared__ unsigned short Ps[4][16 * LP];

  const int tid = threadIdx.x;
  const int l   = tid & 63;
  const int w   = tid >> 6;
  const int q0  = blockIdx.x * 64;
  const int h   = blockIdx.y;
  const int b   = blockIdx.z;
  const int lr  = l & 15;
  const int lk  = (l >> 4) * 8;
  const size_t base = ((size_t)b * SEQ) * D_MODEL + h * DHEAD;

  // ---- stage Q tile (64 x 64) ----
  #pragma unroll
  for (int rr = 0; rr < 2; ++rr) {
    int p = tid + rr * 256;
    int row = p >> 3, col = (p & 7) * 8;
    bf16x8 v = *(const bf16x8*)&mixed[base + (size_t)(q0 + row) * D_MODEL + col];
    *(bf16x8*)&Qs[row * LP + col] = v;
  }
  __syncthreads();
  bf16x8 qf[2];
  qf[0] = *(const bf16x8*)&Qs[(w * 16 + lr) * LP + lk];
  qf[1] = *(const bf16x8*)&Qs[(w * 16 + lr) * LP + 32 + lk];

  float m_i[4], l_i[4];
  f32x4 cacc[4] = {};
  #pragma unroll
  for (int i = 0; i < 4; ++i) { m_i[i] = -1e30f; l_i[i] = 0.f; }

  for (int t0 = 0; t0 < SEQ; t0 += 64) {
    // ---- stage X tile + transpose ----
    #pragma unroll
    for (int rr = 0; rr < 2; ++rr) {
      int p = tid + rr * 256;
      int row = p >> 3, col = (p & 7) * 8;
      bf16x8 v = *(const bf16x8*)&mixed[base + (size_t)(t0 + row) * D_MODEL + col];
      *(bf16x8*)&Xs[row * LP + col] = v;
      #pragma unroll
      for (int j = 0; j < 8; ++j) {              // j-rotated scatter: 2-way banks
        int jj = (j + tid) & 7;
        XTs[(col + jj) * LP + row] = (unsigned short)v[jj];
      }
    }
    __syncthreads();

    // ---- S = Q @ X^T ----
    f32x4 sacc[4] = {};
    #pragma unroll
    for (int kf = 0; kf < 2; ++kf)
      #pragma unroll
      for (int nf = 0; nf < 4; ++nf) {
        bf16x8 kfr = *(const bf16x8*)&Xs[(nf * 16 + lr) * LP + kf * 32 + lk];
        sacc[nf] = __builtin_amdgcn_mfma_f32_16x16x32_bf16(
            qf[kf], kfr, sacc[nf], 0, 0, 0);
      }

    // ---- scale + mask ----
    float s[4][4];
    #pragma unroll
    for (int nf = 0; nf < 4; ++nf) {
      float mk = mask[(size_t)b * SEQ + t0 + nf * 16 + lr];
      #pragma unroll
      for (int i = 0; i < 4; ++i) s[nf][i] = sacc[nf][i] * 0.125f + mk;
    }

    // ---- online softmax: rows (l>>4)*4+i, reduce over 16 lanes ----
    #pragma unroll
    for (int i = 0; i < 4; ++i) {
      float rm = fmaxf(fmaxf(s[0][i], s[1][i]), fmaxf(s[2][i], s[3][i]));
      rm = fmaxf(rm, __shfl_xor(rm, 1));
      rm = fmaxf(rm, __shfl_xor(rm, 2));
      rm = fmaxf(rm, __shfl_xor(rm, 4));
      rm = fmaxf(rm, __shfl_xor(rm, 8));
      float mn    = fmaxf(m_i[i], rm);
      float alpha = __expf(m_i[i] - mn);
      float rs = 0.f;
      #pragma unroll
      for (int nf = 0; nf < 4; ++nf) {
        float pv = __expf(s[nf][i] - mn);
        s[nf][i] = pv;
        rs += pv;
      }
      rs += __shfl_xor(rs, 1);
      rs += __shfl_xor(rs, 2);
      rs += __shfl_xor(rs, 4);
      rs += __shfl_xor(rs, 8);
      l_i[i] = l_i[i] * alpha + rs;
      m_i[i] = mn;
      #pragma unroll
      for (int nf = 0; nf < 4; ++nf) cacc[nf][i] *= alpha;
    }

    // ---- P -> LDS (per-wave region) ----
    const int pr = (l >> 4) * 4;
    #pragma unroll
    for (int nf = 0; nf < 4; ++nf)
      #pragma unroll
      for (int i = 0; i < 4; ++i)
        Ps[w][(pr + i) * LP + nf * 16 + lr] = f2bf(s[nf][i]);
    __syncthreads();

    // ---- ctx += P @ X ----
    bf16x8 pa[2];
    pa[0] = *(const bf16x8*)&Ps[w][lr * LP + lk];
    pa[1] = *(const bf16x8*)&Ps[w][lr * LP + 32 + lk];
    #pragma unroll
    for (int kf = 0; kf < 2; ++kf)
      #pragma unroll
      for (int nf = 0; nf < 4; ++nf) {
        bf16x8 vf = *(const bf16x8*)&XTs[(nf * 16 + lr) * LP + kf * 32 + lk];
        cacc[nf] = __builtin_amdgcn_mfma_f32_16x16x32_bf16(
            pa[kf], vf, cacc[nf], 0, 0, 0);
      }
    __syncthreads();  // before next tile overwrites Xs/XTs
  }

  // ---- normalize + store fp32 ----
  #pragma unroll
  for (int nf = 0; nf < 4; ++nf)
    #pragma unroll
    for (int i = 0; i < 4; ++i) {
      int row = q0 + w * 16 + (l >> 4) * 4 + i;
      int col = h * DHEAD + nf * 16 + lr;
      out[((size_t)b * SEQ + row) * D_MODEL + col] = cacc[nf][i] / l_i[i];
    }
}

// ---------------------------------------------------------------------------
extern "C" void kernel_launch(void* const* d_in, const int* in_sizes, int n_in,
                              void* d_out, int out_size, void* d_ws, size_t ws_size,
                              hipStream_t stream) {
  const float* x    = (const float*)d_in[0];
  const float* mask = (const float*)d_in[1];
  const float* W    = (const float*)d_in[2];
  const float* bias = (const float*)d_in[3];
  float* out        = (float*)d_out;

  unsigned short* mixed = (unsigned short*)d_ws;  // [8192][768] bf16 = 12.6 MB

  dim3 gp(8192 / 128, D_MODEL / 128);             // (64, 6)
  proj_kernel<<<gp, 256, 0, stream>>>(x, W, bias, mixed);

  dim3 ga(SEQ / 64, NHEAD, BATCH);                // (16, 12, 8)
  attn_kernel<<<ga, 256, 0, stream>>>(mixed, mask, out);
}